// Round 1
// baseline (219.985 us; speedup 1.0000x reference)
//
#include <hip/hip_runtime.h>
#include <math.h>

#define EMB 256

// ---------------------------------------------------------------------------
// K1: gate scores  s[i] = values[i,:] . gate_w + gate_b
// One wave (64 lanes) per row; each lane holds 4 consecutive floats (float4).
// ---------------------------------------------------------------------------
__global__ void __launch_bounds__(256) k_gate(const float* __restrict__ vals,
                                              const float* __restrict__ gate_w,
                                              const float* __restrict__ gate_b,
                                              float* __restrict__ s, int n) {
    const int lane = threadIdx.x & 63;
    const int wid  = blockIdx.x * (blockDim.x >> 6) + (threadIdx.x >> 6);
    const int nw   = gridDim.x * (blockDim.x >> 6);
    const float4 gw = *reinterpret_cast<const float4*>(gate_w + lane * 4);
    const float  gb = gate_b[0];
    for (int row = wid; row < n; row += nw) {
        float4 v = *reinterpret_cast<const float4*>(vals + (size_t)row * EMB + lane * 4);
        float d = v.x * gw.x + v.y * gw.y + v.z * gw.z + v.w * gw.w;
        #pragma unroll
        for (int o = 32; o; o >>= 1) d += __shfl_down(d, o);
        if (lane == 0) s[row] = d + gb;
    }
}

// ---------------------------------------------------------------------------
// K2: segment bounds via binary search (indices are sorted).
// seg_start[g] = first i with idx[i] >= g;  seg_start[G] = n.
// ---------------------------------------------------------------------------
__global__ void k_bounds(const int* __restrict__ idx, int* __restrict__ seg_start,
                         int n, int g) {
    int t = blockIdx.x * blockDim.x + threadIdx.x;
    if (t > g) return;
    int lo = 0, hi = n;
    while (lo < hi) {
        int mid = (lo + hi) >> 1;
        if (idx[mid] < t) lo = mid + 1; else hi = mid;
    }
    seg_start[t] = lo;
}

// ---------------------------------------------------------------------------
// K4: per-segment softmax + weighted vector sum.
// One block (256 thr = 4 waves) per segment.
//   phase 1: block max of s over segment
//   phase 2: denom = sum exp(s - m)
//   phase 3: wvec[g,:] = sum_i  exp(s_i - m)/denom * values[i,:]
// Accumulation: wave w handles rows j = w, w+4, ...; lane owns dims 4*lane..+3
// (float4 global loads); cross-wave reduce through LDS at the end.
// ---------------------------------------------------------------------------
__global__ void __launch_bounds__(256) k_seg(const float* __restrict__ vals,
                                             const float* __restrict__ s,
                                             const int* __restrict__ seg_start,
                                             float* __restrict__ wvec) {
    const int g = blockIdx.x;
    const int start = seg_start[g], end = seg_start[g + 1];
    const int cnt = end - start;
    const int t = threadIdx.x;
    const int lane = t & 63, w = t >> 6;

    __shared__ float red[4];
    __shared__ float bc[2];
    __shared__ float w_s[256];
    __shared__ float partial[4][EMB];

    if (cnt <= 0) {                 // empty segment -> exact zeros
        wvec[(size_t)g * EMB + t] = 0.0f;
        return;
    }

    // ---- phase 1: max ----
    float m = -INFINITY;
    for (int i = start + t; i < end; i += 256) m = fmaxf(m, s[i]);
    #pragma unroll
    for (int o = 32; o; o >>= 1) m = fmaxf(m, __shfl_down(m, o));
    if (lane == 0) red[w] = m;
    __syncthreads();
    if (t == 0) bc[0] = fmaxf(fmaxf(red[0], red[1]), fmaxf(red[2], red[3]));
    __syncthreads();
    m = bc[0];

    // ---- phase 2: denom ----
    float d = 0.0f;
    for (int i = start + t; i < end; i += 256) d += expf(s[i] - m);
    #pragma unroll
    for (int o = 32; o; o >>= 1) d += __shfl_down(d, o);
    if (lane == 0) red[w] = d;
    __syncthreads();
    if (t == 0) bc[1] = red[0] + red[1] + red[2] + red[3];
    __syncthreads();
    const float inv_d = 1.0f / bc[1];

    // ---- phase 3: weighted accumulation ----
    float4 acc = {0.f, 0.f, 0.f, 0.f};
    for (int c0 = start; c0 < end; c0 += 256) {
        const int chunk = min(256, end - c0);
        __syncthreads();
        w_s[t] = (t < chunk) ? expf(s[c0 + t] - m) * inv_d : 0.0f;
        __syncthreads();
        for (int j = w; j < chunk; j += 4) {
            const float wj = w_s[j];
            float4 v = *reinterpret_cast<const float4*>(
                vals + (size_t)(c0 + j) * EMB + lane * 4);
            acc.x += wj * v.x; acc.y += wj * v.y;
            acc.z += wj * v.z; acc.w += wj * v.w;
        }
    }
    *reinterpret_cast<float4*>(&partial[w][lane * 4]) = acc;
    __syncthreads();
    wvec[(size_t)g * EMB + t] =
        partial[0][t] + partial[1][t] + partial[2][t] + partial[3][t];
}

// ---------------------------------------------------------------------------
// K5: out[G,256] = wvec @ attn_w + (cnt>0) * attn_b
// 64x64 tile per block, 256 threads, 4x4 register blocking, f32 VALU.
// A_s padded to 68 to de-conflict column reads.
// ---------------------------------------------------------------------------
__global__ void __launch_bounds__(256) k_gemm(const float* __restrict__ A,
                                              const float* __restrict__ W,
                                              const float* __restrict__ bias,
                                              const int* __restrict__ seg_start,
                                              float* __restrict__ out) {
    __shared__ float A_s[64][68];
    __shared__ float B_s[64][64];
    const int bid = blockIdx.x;
    const int row0 = (bid >> 2) * 64;
    const int col0 = (bid & 3) * 64;
    const int t = threadIdx.x;
    const int ty = t >> 4, tx = t & 15;

    float acc[4][4] = {};

    for (int kc = 0; kc < EMB; kc += 64) {
        #pragma unroll
        for (int l = t; l < 64 * 16; l += 256) {
            int r = l >> 4, c4 = (l & 15) << 2;
            float4 v = *reinterpret_cast<const float4*>(
                A + (size_t)(row0 + r) * EMB + kc + c4);
            *reinterpret_cast<float4*>(&A_s[r][c4]) = v;
        }
        #pragma unroll
        for (int l = t; l < 64 * 16; l += 256) {
            int r = l >> 4, c4 = (l & 15) << 2;
            *reinterpret_cast<float4*>(&B_s[r][c4]) =
                *reinterpret_cast<const float4*>(
                    W + (size_t)(kc + r) * EMB + col0 + c4);
        }
        __syncthreads();

        #pragma unroll
        for (int k = 0; k < 64; k += 4) {
            float a[4][4], b[4][4];
            #pragma unroll
            for (int i = 0; i < 4; ++i)
                *reinterpret_cast<float4*>(a[i]) =
                    *reinterpret_cast<const float4*>(&A_s[ty * 4 + i][k]);
            #pragma unroll
            for (int kk = 0; kk < 4; ++kk)
                *reinterpret_cast<float4*>(b[kk]) =
                    *reinterpret_cast<const float4*>(&B_s[k + kk][tx * 4]);
            #pragma unroll
            for (int i = 0; i < 4; ++i)
                #pragma unroll
                for (int kk = 0; kk < 4; ++kk)
                    #pragma unroll
                    for (int j = 0; j < 4; ++j)
                        acc[i][j] += a[i][kk] * b[kk][j];
        }
        __syncthreads();
    }

    const float4 b4 = *reinterpret_cast<const float4*>(bias + col0 + tx * 4);
    #pragma unroll
    for (int i = 0; i < 4; ++i) {
        const int r = row0 + ty * 4 + i;
        const float bs = (seg_start[r + 1] - seg_start[r]) > 0 ? 1.0f : 0.0f;
        float4 o;
        o.x = acc[i][0] + bs * b4.x;
        o.y = acc[i][1] + bs * b4.y;
        o.z = acc[i][2] + bs * b4.z;
        o.w = acc[i][3] + bs * b4.w;
        *reinterpret_cast<float4*>(out + (size_t)r * EMB + col0 + tx * 4) = o;
    }
}

// ---------------------------------------------------------------------------
extern "C" void kernel_launch(void* const* d_in, const int* in_sizes, int n_in,
                              void* d_out, int out_size, void* d_ws, size_t ws_size,
                              hipStream_t stream) {
    const float* vals   = (const float*)d_in[0];
    const int*   idx    = (const int*)d_in[1];
    const float* gate_w = (const float*)d_in[3];
    const float* gate_b = (const float*)d_in[4];
    const float* attn_w = (const float*)d_in[5];
    const float* attn_b = (const float*)d_in[6];
    float* out = (float*)d_out;

    const int n = in_sizes[1];          // number of nodes
    const int g = out_size / EMB;       // number of graphs (4096)

    // workspace layout (all 16B-aligned)
    float* s = (float*)d_ws;                          // n floats
    int*   seg_start = (int*)(s + n);                 // g+1 ints (n*4 is 16B-aligned)
    float* wvec = (float*)(seg_start + ((g + 1 + 3) & ~3)); // g*EMB floats

    k_gate<<<2048, 256, 0, stream>>>(vals, gate_w, gate_b, s, n);
    k_bounds<<<(g + 256) / 256, 256, 0, stream>>>(idx, seg_start, n, g);
    k_seg<<<g, 256, 0, stream>>>(vals, s, seg_start, wvec);
    k_gemm<<<(g / 64) * 4, 256, 0, stream>>>(wvec, attn_w, attn_b, seg_start, out);
}

// Round 2
// 131.580 us; speedup vs baseline: 1.6719x; 1.6719x over previous
//
#include <hip/hip_runtime.h>
#include <math.h>

#define EMB 256

// ---------------------------------------------------------------------------
// K2: segment bounds via binary search (indices are sorted).
// seg_start[g] = first i with idx[i] >= g;  seg_start[G] = n.
// ---------------------------------------------------------------------------
__global__ void k_bounds(const int* __restrict__ idx, int* __restrict__ seg_start,
                         int n, int g) {
    int t = blockIdx.x * blockDim.x + threadIdx.x;
    if (t > g) return;
    int lo = 0, hi = n;
    while (lo < hi) {
        int mid = (lo + hi) >> 1;
        if (idx[mid] < t) lo = mid + 1; else hi = mid;
    }
    seg_start[t] = lo;
}

// ---------------------------------------------------------------------------
// K_fused: single pass over values. Per segment (one block, 4 waves):
// each wave streams rows j = w, w+4, ... computing the gate score s_j
// in-register (float4 dot + __shfl_xor butterfly -> s_j in ALL lanes, so the
// new-max rescale branch is wave-uniform), maintaining online-softmax state
// (m, d, acc[4]/lane). Cross-wave combine through LDS:
//   M = max_w m_w;  out = (sum_w acc_w * e^{m_w-M}) / (sum_w d_w * e^{m_w-M})
// One 512 MB read of values total (vs 2x in the unfused version).
// ---------------------------------------------------------------------------
__global__ void __launch_bounds__(256) k_fused(const float* __restrict__ vals,
                                               const float* __restrict__ gate_w,
                                               const float* __restrict__ gate_b,
                                               const int* __restrict__ seg_start,
                                               float* __restrict__ wvec) {
    const int g = blockIdx.x;
    const int start = seg_start[g], end = seg_start[g + 1];
    const int cnt = end - start;
    const int t = threadIdx.x;
    const int lane = t & 63, w = t >> 6;

    __shared__ float m_s[4], d_s[4];
    __shared__ float partial[4][EMB];

    if (cnt <= 0) {                 // empty segment -> exact zeros
        wvec[(size_t)g * EMB + t] = 0.0f;
        return;
    }

    const float4 gw = *reinterpret_cast<const float4*>(gate_w + lane * 4);
    const float  gb = gate_b[0];

    float m = -INFINITY, d = 0.0f;
    float4 acc = {0.f, 0.f, 0.f, 0.f};

    for (int j = start + w; j < end; j += 4) {
        float4 v = *reinterpret_cast<const float4*>(vals + (size_t)j * EMB + lane * 4);
        float si = v.x * gw.x + v.y * gw.y + v.z * gw.z + v.w * gw.w;
        #pragma unroll
        for (int o = 1; o < 64; o <<= 1) si += __shfl_xor(si, o);
        si += gb;
        if (si > m) {               // wave-uniform branch (si identical in all lanes)
            const float scale = expf(m - si);   // first iter: exp(-inf)=0
            d *= scale;
            acc.x *= scale; acc.y *= scale; acc.z *= scale; acc.w *= scale;
            m = si;
        }
        const float p = expf(si - m);
        d += p;
        acc.x += p * v.x; acc.y += p * v.y; acc.z += p * v.z; acc.w += p * v.w;
    }

    // ---- cross-wave combine ----
    if (lane == 0) m_s[w] = m;      // empty waves (cnt<=w) contribute -inf
    __syncthreads();
    const float M = fmaxf(fmaxf(m_s[0], m_s[1]), fmaxf(m_s[2], m_s[3]));
    const float f = expf(m - M);    // 0 for empty waves; M finite since cnt>0
    if (lane == 0) d_s[w] = d * f;
    acc.x *= f; acc.y *= f; acc.z *= f; acc.w *= f;
    *reinterpret_cast<float4*>(&partial[w][lane * 4]) = acc;
    __syncthreads();
    const float dt = d_s[0] + d_s[1] + d_s[2] + d_s[3];
    wvec[(size_t)g * EMB + t] =
        (partial[0][t] + partial[1][t] + partial[2][t] + partial[3][t]) / dt;
}

// ---------------------------------------------------------------------------
// K5: out[G,256] = wvec @ attn_w + (cnt>0) * attn_b
// 64x64 tile per block, 256 threads, 4x4 register blocking, f32 VALU.
// A_s padded to 68 to de-conflict column reads.
// ---------------------------------------------------------------------------
__global__ void __launch_bounds__(256) k_gemm(const float* __restrict__ A,
                                              const float* __restrict__ W,
                                              const float* __restrict__ bias,
                                              const int* __restrict__ seg_start,
                                              float* __restrict__ out) {
    __shared__ float A_s[64][68];
    __shared__ float B_s[64][64];
    const int bid = blockIdx.x;
    const int row0 = (bid >> 2) * 64;
    const int col0 = (bid & 3) * 64;
    const int t = threadIdx.x;
    const int ty = t >> 4, tx = t & 15;

    float acc[4][4] = {};

    for (int kc = 0; kc < EMB; kc += 64) {
        #pragma unroll
        for (int l = t; l < 64 * 16; l += 256) {
            int r = l >> 4, c4 = (l & 15) << 2;
            float4 v = *reinterpret_cast<const float4*>(
                A + (size_t)(row0 + r) * EMB + kc + c4);
            *reinterpret_cast<float4*>(&A_s[r][c4]) = v;
        }
        #pragma unroll
        for (int l = t; l < 64 * 16; l += 256) {
            int r = l >> 4, c4 = (l & 15) << 2;
            *reinterpret_cast<float4*>(&B_s[r][c4]) =
                *reinterpret_cast<const float4*>(
                    W + (size_t)(kc + r) * EMB + col0 + c4);
        }
        __syncthreads();

        #pragma unroll
        for (int k = 0; k < 64; k += 4) {
            float a[4][4], b[4][4];
            #pragma unroll
            for (int i = 0; i < 4; ++i)
                *reinterpret_cast<float4*>(a[i]) =
                    *reinterpret_cast<const float4*>(&A_s[ty * 4 + i][k]);
            #pragma unroll
            for (int kk = 0; kk < 4; ++kk)
                *reinterpret_cast<float4*>(b[kk]) =
                    *reinterpret_cast<const float4*>(&B_s[k + kk][tx * 4]);
            #pragma unroll
            for (int i = 0; i < 4; ++i)
                #pragma unroll
                for (int kk = 0; kk < 4; ++kk)
                    #pragma unroll
                    for (int j = 0; j < 4; ++j)
                        acc[i][j] += a[i][kk] * b[kk][j];
        }
        __syncthreads();
    }

    const float4 b4 = *reinterpret_cast<const float4*>(bias + col0 + tx * 4);
    #pragma unroll
    for (int i = 0; i < 4; ++i) {
        const int r = row0 + ty * 4 + i;
        const float bs = (seg_start[r + 1] - seg_start[r]) > 0 ? 1.0f : 0.0f;
        float4 o;
        o.x = acc[i][0] + bs * b4.x;
        o.y = acc[i][1] + bs * b4.y;
        o.z = acc[i][2] + bs * b4.z;
        o.w = acc[i][3] + bs * b4.w;
        *reinterpret_cast<float4*>(out + (size_t)r * EMB + col0 + tx * 4) = o;
    }
}

// ---------------------------------------------------------------------------
extern "C" void kernel_launch(void* const* d_in, const int* in_sizes, int n_in,
                              void* d_out, int out_size, void* d_ws, size_t ws_size,
                              hipStream_t stream) {
    const float* vals   = (const float*)d_in[0];
    const int*   idx    = (const int*)d_in[1];
    const float* gate_w = (const float*)d_in[3];
    const float* gate_b = (const float*)d_in[4];
    const float* attn_w = (const float*)d_in[5];
    const float* attn_b = (const float*)d_in[6];
    float* out = (float*)d_out;

    const int n = in_sizes[1];          // number of nodes
    const int g = out_size / EMB;       // number of graphs (4096)

    // workspace layout (16B-aligned)
    int*   seg_start = (int*)d_ws;                         // g+1 ints
    float* wvec = (float*)((char*)d_ws + (((g + 1) * 4 + 15) & ~15)); // g*EMB floats

    k_bounds<<<(g + 256) / 256, 256, 0, stream>>>(idx, seg_start, n, g);
    k_fused<<<g, 256, 0, stream>>>(vals, gate_w, gate_b, seg_start, wvec);
    k_gemm<<<(g / 64) * 4, 256, 0, stream>>>(wvec, attn_w, attn_b, seg_start, out);
}

// Round 4
// 110.404 us; speedup vs baseline: 1.9925x; 1.1918x over previous
//
#include <hip/hip_runtime.h>
#include <math.h>

#define EMB 256

typedef float f32x4 __attribute__((ext_vector_type(4)));   // native vector for nontemporal builtins

// ---------------------------------------------------------------------------
// K2: segment bounds via binary search (indices are sorted).
// seg_start[g] = first i with idx[i] >= g;  seg_start[G] = n.
// ---------------------------------------------------------------------------
__global__ void k_bounds(const int* __restrict__ idx, int* __restrict__ seg_start,
                         int n, int g) {
    int t = blockIdx.x * blockDim.x + threadIdx.x;
    if (t > g) return;
    int lo = 0, hi = n;
    while (lo < hi) {
        int mid = (lo + hi) >> 1;
        if (idx[mid] < t) lo = mid + 1; else hi = mid;
    }
    seg_start[t] = lo;
}

// ---------------------------------------------------------------------------
// K_fused: single pass over values with online softmax.
// One block (4 waves) per segment. Wave w streams 4 consecutive rows per
// iteration (rows start+16k+4w .. +3): 4 independent float4 loads in flight
// (4 KB/wave MLP), 4 interleaved shfl_xor butterflies (s_j broadcast to all
// lanes -> rescale branch wave-uniform), ONE rescale per 4 rows.
// Dead rows (tail): v=0, s=-inf -> p=0, exact no-op. Cross-wave combine in LDS.
// ---------------------------------------------------------------------------
__global__ void __launch_bounds__(256) k_fused(const float* __restrict__ vals,
                                               const float* __restrict__ gate_w,
                                               const float* __restrict__ gate_b,
                                               const int* __restrict__ seg_start,
                                               float* __restrict__ wvec) {
    const int g = blockIdx.x;
    const int start = seg_start[g], end = seg_start[g + 1];
    const int cnt = end - start;
    const int t = threadIdx.x;
    const int lane = t & 63, w = t >> 6;

    __shared__ float m_s[4], d_s[4];
    __shared__ float partial[4][EMB];

    if (cnt <= 0) {                 // empty segment -> exact zeros
        wvec[(size_t)g * EMB + t] = 0.0f;
        return;
    }

    const f32x4 gw = *reinterpret_cast<const f32x4*>(gate_w + lane * 4);
    const float gb = gate_b[0];

    float m = -INFINITY, d = 0.0f;
    f32x4 acc = {0.f, 0.f, 0.f, 0.f};

    for (int j = start + w * 4; j < end; j += 16) {
        // ---- issue up to 4 independent row loads ----
        f32x4 v0 = {0,0,0,0}, v1 = {0,0,0,0}, v2 = {0,0,0,0}, v3 = {0,0,0,0};
        const float* p0 = vals + (size_t)j * EMB + lane * 4;
        if (j + 3 < end) {          // fast path (wave-uniform)
            v0 = __builtin_nontemporal_load(reinterpret_cast<const f32x4*>(p0));
            v1 = __builtin_nontemporal_load(reinterpret_cast<const f32x4*>(p0 + EMB));
            v2 = __builtin_nontemporal_load(reinterpret_cast<const f32x4*>(p0 + 2 * EMB));
            v3 = __builtin_nontemporal_load(reinterpret_cast<const f32x4*>(p0 + 3 * EMB));
        } else {
            v0 = __builtin_nontemporal_load(reinterpret_cast<const f32x4*>(p0));
            if (j + 1 < end) v1 = __builtin_nontemporal_load(reinterpret_cast<const f32x4*>(p0 + EMB));
            if (j + 2 < end) v2 = __builtin_nontemporal_load(reinterpret_cast<const f32x4*>(p0 + 2 * EMB));
        }

        // ---- 4 gate dots, butterflies interleaved for ILP ----
        float s0 = v0.x * gw.x + v0.y * gw.y + v0.z * gw.z + v0.w * gw.w;
        float s1 = v1.x * gw.x + v1.y * gw.y + v1.z * gw.z + v1.w * gw.w;
        float s2 = v2.x * gw.x + v2.y * gw.y + v2.z * gw.z + v2.w * gw.w;
        float s3 = v3.x * gw.x + v3.y * gw.y + v3.z * gw.z + v3.w * gw.w;
        #pragma unroll
        for (int o = 1; o < 64; o <<= 1) {
            s0 += __shfl_xor(s0, o);
            s1 += __shfl_xor(s1, o);
            s2 += __shfl_xor(s2, o);
            s3 += __shfl_xor(s3, o);
        }
        s0 += gb; s1 += gb; s2 += gb; s3 += gb;
        if (j + 3 >= end) {         // kill dead rows (tail only, wave-uniform)
            if (j + 1 >= end) s1 = -INFINITY;
            if (j + 2 >= end) s2 = -INFINITY;
            s3 = -INFINITY;
        }

        // ---- one online-softmax rescale per 4 rows ----
        const float mx = fmaxf(fmaxf(s0, s1), fmaxf(s2, s3));
        if (mx > m) {               // wave-uniform
            const float sc = __expf(m - mx);    // first iter: exp(-inf)=0
            d *= sc;
            acc.x *= sc; acc.y *= sc; acc.z *= sc; acc.w *= sc;
            m = mx;
        }
        const float e0 = __expf(s0 - m), e1 = __expf(s1 - m);
        const float e2 = __expf(s2 - m), e3 = __expf(s3 - m);
        d += (e0 + e1) + (e2 + e3);
        acc.x += e0 * v0.x + e1 * v1.x + e2 * v2.x + e3 * v3.x;
        acc.y += e0 * v0.y + e1 * v1.y + e2 * v2.y + e3 * v3.y;
        acc.z += e0 * v0.z + e1 * v1.z + e2 * v2.z + e3 * v3.z;
        acc.w += e0 * v0.w + e1 * v1.w + e2 * v2.w + e3 * v3.w;
    }

    // ---- cross-wave combine ----
    if (lane == 0) m_s[w] = m;      // waves with no rows contribute -inf
    __syncthreads();
    const float M = fmaxf(fmaxf(m_s[0], m_s[1]), fmaxf(m_s[2], m_s[3]));
    const float f = __expf(m - M);  // 0 for empty waves; M finite since cnt>0
    if (lane == 0) d_s[w] = d * f;
    acc.x *= f; acc.y *= f; acc.z *= f; acc.w *= f;
    *reinterpret_cast<f32x4*>(&partial[w][lane * 4]) = acc;
    __syncthreads();
    const float dt = d_s[0] + d_s[1] + d_s[2] + d_s[3];
    wvec[(size_t)g * EMB + t] =
        (partial[0][t] + partial[1][t] + partial[2][t] + partial[3][t]) / dt;
}

// ---------------------------------------------------------------------------
// K5: out[G,256] = wvec @ attn_w + (cnt>0) * attn_b
// 64x64 tile per block, 256 threads, 4x4 register blocking, f32 VALU.
// A_s padded to 68 to de-conflict column reads.
// ---------------------------------------------------------------------------
__global__ void __launch_bounds__(256) k_gemm(const float* __restrict__ A,
                                              const float* __restrict__ W,
                                              const float* __restrict__ bias,
                                              const int* __restrict__ seg_start,
                                              float* __restrict__ out) {
    __shared__ float A_s[64][68];
    __shared__ float B_s[64][64];
    const int bid = blockIdx.x;
    const int row0 = (bid >> 2) * 64;
    const int col0 = (bid & 3) * 64;
    const int t = threadIdx.x;
    const int ty = t >> 4, tx = t & 15;

    float acc[4][4] = {};

    for (int kc = 0; kc < EMB; kc += 64) {
        #pragma unroll
        for (int l = t; l < 64 * 16; l += 256) {
            int r = l >> 4, c4 = (l & 15) << 2;
            float4 v = *reinterpret_cast<const float4*>(
                A + (size_t)(row0 + r) * EMB + kc + c4);
            *reinterpret_cast<float4*>(&A_s[r][c4]) = v;
        }
        #pragma unroll
        for (int l = t; l < 64 * 16; l += 256) {
            int r = l >> 4, c4 = (l & 15) << 2;
            *reinterpret_cast<float4*>(&B_s[r][c4]) =
                *reinterpret_cast<const float4*>(
                    W + (size_t)(kc + r) * EMB + col0 + c4);
        }
        __syncthreads();

        #pragma unroll
        for (int k = 0; k < 64; k += 4) {
            float a[4][4], b[4][4];
            #pragma unroll
            for (int i = 0; i < 4; ++i)
                *reinterpret_cast<float4*>(a[i]) =
                    *reinterpret_cast<const float4*>(&A_s[ty * 4 + i][k]);
            #pragma unroll
            for (int kk = 0; kk < 4; ++kk)
                *reinterpret_cast<float4*>(b[kk]) =
                    *reinterpret_cast<const float4*>(&B_s[k + kk][tx * 4]);
            #pragma unroll
            for (int i = 0; i < 4; ++i)
                #pragma unroll
                for (int kk = 0; kk < 4; ++kk)
                    #pragma unroll
                    for (int j = 0; j < 4; ++j)
                        acc[i][j] += a[i][kk] * b[kk][j];
        }
        __syncthreads();
    }

    const float4 b4 = *reinterpret_cast<const float4*>(bias + col0 + tx * 4);
    #pragma unroll
    for (int i = 0; i < 4; ++i) {
        const int r = row0 + ty * 4 + i;
        const float bs = (seg_start[r + 1] - seg_start[r]) > 0 ? 1.0f : 0.0f;
        float4 o;
        o.x = acc[i][0] + bs * b4.x;
        o.y = acc[i][1] + bs * b4.y;
        o.z = acc[i][2] + bs * b4.z;
        o.w = acc[i][3] + bs * b4.w;
        *reinterpret_cast<float4*>(out + (size_t)r * EMB + col0 + tx * 4) = o;
    }
}

// ---------------------------------------------------------------------------
extern "C" void kernel_launch(void* const* d_in, const int* in_sizes, int n_in,
                              void* d_out, int out_size, void* d_ws, size_t ws_size,
                              hipStream_t stream) {
    const float* vals   = (const float*)d_in[0];
    const int*   idx    = (const int*)d_in[1];
    const float* gate_w = (const float*)d_in[3];
    const float* gate_b = (const float*)d_in[4];
    const float* attn_w = (const float*)d_in[5];
    const float* attn_b = (const float*)d_in[6];
    float* out = (float*)d_out;

    const int n = in_sizes[1];          // number of nodes
    const int g = out_size / EMB;       // number of graphs (4096)

    // workspace layout (16B-aligned)
    int*   seg_start = (int*)d_ws;                         // g+1 ints
    float* wvec = (float*)((char*)d_ws + (((g + 1) * 4 + 15) & ~15)); // g*EMB floats

    k_bounds<<<(g + 256) / 256, 256, 0, stream>>>(idx, seg_start, n, g);
    k_fused<<<g, 256, 0, stream>>>(vals, gate_w, gate_b, seg_start, wvec);
    k_gemm<<<(g / 64) * 4, 256, 0, stream>>>(wvec, attn_w, attn_b, seg_start, out);
}

// Round 5
// 109.069 us; speedup vs baseline: 2.0169x; 1.0122x over previous
//
#include <hip/hip_runtime.h>
#include <math.h>

#define EMB 256

typedef float f32x4 __attribute__((ext_vector_type(4)));   // native vector for nontemporal builtins

// ---------------------------------------------------------------------------
// K2: segment bounds via binary search (indices are sorted).
// seg_start[g] = first i with idx[i] >= g;  seg_start[G] = n.
// ---------------------------------------------------------------------------
__global__ void k_bounds(const int* __restrict__ idx, int* __restrict__ seg_start,
                         int n, int g) {
    int t = blockIdx.x * blockDim.x + threadIdx.x;
    if (t > g) return;
    int lo = 0, hi = n;
    while (lo < hi) {
        int mid = (lo + hi) >> 1;
        if (idx[mid] < t) lo = mid + 1; else hi = mid;
    }
    seg_start[t] = lo;
}

// ---------------------------------------------------------------------------
// K_fused: single pass over values with online softmax.
// One block (4 waves) per segment. Wave w streams 8 consecutive rows per
// iteration (rows start+32k+8w .. +7): 8 independent float4 loads in flight
// (8 KB/wave MLP), 8 interleaved shfl_xor butterflies (s_j broadcast to all
// lanes -> rescale branch wave-uniform), ONE rescale per 8 rows.
// Dead rows (tail): v=0, s=-inf -> p=0, exact no-op. Cross-wave combine in LDS.
// ---------------------------------------------------------------------------
__global__ void __launch_bounds__(256) k_fused(const float* __restrict__ vals,
                                               const float* __restrict__ gate_w,
                                               const float* __restrict__ gate_b,
                                               const int* __restrict__ seg_start,
                                               float* __restrict__ wvec) {
    const int g = blockIdx.x;
    const int start = seg_start[g], end = seg_start[g + 1];
    const int cnt = end - start;
    const int t = threadIdx.x;
    const int lane = t & 63, w = t >> 6;

    __shared__ float m_s[4], d_s[4];
    __shared__ float partial[4][EMB];

    if (cnt <= 0) {                 // empty segment -> exact zeros
        wvec[(size_t)g * EMB + t] = 0.0f;
        return;
    }

    const f32x4 gw = *reinterpret_cast<const f32x4*>(gate_w + lane * 4);
    const float gb = gate_b[0];

    float m = -INFINITY, d = 0.0f;
    f32x4 acc = {0.f, 0.f, 0.f, 0.f};

    for (int j = start + w * 8; j < end; j += 32) {
        // ---- issue up to 8 independent row loads (8 KB/wave in flight) ----
        f32x4 v[8];
        #pragma unroll
        for (int r = 0; r < 8; ++r) v[r] = (f32x4){0.f, 0.f, 0.f, 0.f};
        const float* p0 = vals + (size_t)j * EMB + lane * 4;
        if (j + 7 < end) {          // fast path (wave-uniform)
            #pragma unroll
            for (int r = 0; r < 8; ++r)
                v[r] = __builtin_nontemporal_load(
                    reinterpret_cast<const f32x4*>(p0 + r * EMB));
        } else {
            #pragma unroll
            for (int r = 0; r < 8; ++r)
                if (j + r < end)
                    v[r] = __builtin_nontemporal_load(
                        reinterpret_cast<const f32x4*>(p0 + r * EMB));
        }

        // ---- 8 gate dots, butterflies interleaved for ILP ----
        float s[8];
        #pragma unroll
        for (int r = 0; r < 8; ++r)
            s[r] = v[r].x * gw.x + v[r].y * gw.y + v[r].z * gw.z + v[r].w * gw.w;
        #pragma unroll
        for (int o = 1; o < 64; o <<= 1) {
            #pragma unroll
            for (int r = 0; r < 8; ++r) s[r] += __shfl_xor(s[r], o);
        }
        #pragma unroll
        for (int r = 0; r < 8; ++r) s[r] += gb;
        if (j + 7 >= end) {         // kill dead rows (tail only, wave-uniform)
            #pragma unroll
            for (int r = 1; r < 8; ++r)
                if (j + r >= end) s[r] = -INFINITY;
        }

        // ---- one online-softmax rescale per 8 rows ----
        float mx = s[0];
        #pragma unroll
        for (int r = 1; r < 8; ++r) mx = fmaxf(mx, s[r]);
        if (mx > m) {               // wave-uniform
            const float sc = __expf(m - mx);    // first iter: exp(-inf)=0
            d *= sc;
            acc.x *= sc; acc.y *= sc; acc.z *= sc; acc.w *= sc;
            m = mx;
        }
        float e[8];
        #pragma unroll
        for (int r = 0; r < 8; ++r) e[r] = __expf(s[r] - m);
        #pragma unroll
        for (int r = 0; r < 8; ++r) d += e[r];
        #pragma unroll
        for (int r = 0; r < 8; ++r) {
            acc.x += e[r] * v[r].x;
            acc.y += e[r] * v[r].y;
            acc.z += e[r] * v[r].z;
            acc.w += e[r] * v[r].w;
        }
    }

    // ---- cross-wave combine ----
    if (lane == 0) m_s[w] = m;      // waves with no rows contribute -inf
    __syncthreads();
    const float M = fmaxf(fmaxf(m_s[0], m_s[1]), fmaxf(m_s[2], m_s[3]));
    const float f = __expf(m - M);  // 0 for empty waves; M finite since cnt>0
    if (lane == 0) d_s[w] = d * f;
    acc.x *= f; acc.y *= f; acc.z *= f; acc.w *= f;
    *reinterpret_cast<f32x4*>(&partial[w][lane * 4]) = acc;
    __syncthreads();
    const float dt = d_s[0] + d_s[1] + d_s[2] + d_s[3];
    wvec[(size_t)g * EMB + t] =
        (partial[0][t] + partial[1][t] + partial[2][t] + partial[3][t]) / dt;
}

// ---------------------------------------------------------------------------
// K5: out[G,256] = wvec @ attn_w + (cnt>0) * attn_b
// 64x64 tile per block, 256 threads, 4x4 register blocking, f32 VALU.
// A_s padded to 68 to de-conflict column reads.
// ---------------------------------------------------------------------------
__global__ void __launch_bounds__(256) k_gemm(const float* __restrict__ A,
                                              const float* __restrict__ W,
                                              const float* __restrict__ bias,
                                              const int* __restrict__ seg_start,
                                              float* __restrict__ out) {
    __shared__ float A_s[64][68];
    __shared__ float B_s[64][64];
    const int bid = blockIdx.x;
    const int row0 = (bid >> 2) * 64;
    const int col0 = (bid & 3) * 64;
    const int t = threadIdx.x;
    const int ty = t >> 4, tx = t & 15;

    float acc[4][4] = {};

    for (int kc = 0; kc < EMB; kc += 64) {
        #pragma unroll
        for (int l = t; l < 64 * 16; l += 256) {
            int r = l >> 4, c4 = (l & 15) << 2;
            float4 v = *reinterpret_cast<const float4*>(
                A + (size_t)(row0 + r) * EMB + kc + c4);
            *reinterpret_cast<float4*>(&A_s[r][c4]) = v;
        }
        #pragma unroll
        for (int l = t; l < 64 * 16; l += 256) {
            int r = l >> 4, c4 = (l & 15) << 2;
            *reinterpret_cast<float4*>(&B_s[r][c4]) =
                *reinterpret_cast<const float4*>(
                    W + (size_t)(kc + r) * EMB + col0 + c4);
        }
        __syncthreads();

        #pragma unroll
        for (int k = 0; k < 64; k += 4) {
            float a[4][4], b[4][4];
            #pragma unroll
            for (int i = 0; i < 4; ++i)
                *reinterpret_cast<float4*>(a[i]) =
                    *reinterpret_cast<const float4*>(&A_s[ty * 4 + i][k]);
            #pragma unroll
            for (int kk = 0; kk < 4; ++kk)
                *reinterpret_cast<float4*>(b[kk]) =
                    *reinterpret_cast<const float4*>(&B_s[k + kk][tx * 4]);
            #pragma unroll
            for (int i = 0; i < 4; ++i)
                #pragma unroll
                for (int kk = 0; kk < 4; ++kk)
                    #pragma unroll
                    for (int j = 0; j < 4; ++j)
                        acc[i][j] += a[i][kk] * b[kk][j];
        }
        __syncthreads();
    }

    const float4 b4 = *reinterpret_cast<const float4*>(bias + col0 + tx * 4);
    #pragma unroll
    for (int i = 0; i < 4; ++i) {
        const int r = row0 + ty * 4 + i;
        const float bs = (seg_start[r + 1] - seg_start[r]) > 0 ? 1.0f : 0.0f;
        float4 o;
        o.x = acc[i][0] + bs * b4.x;
        o.y = acc[i][1] + bs * b4.y;
        o.z = acc[i][2] + bs * b4.z;
        o.w = acc[i][3] + bs * b4.w;
        *reinterpret_cast<float4*>(out + (size_t)r * EMB + col0 + tx * 4) = o;
    }
}

// ---------------------------------------------------------------------------
extern "C" void kernel_launch(void* const* d_in, const int* in_sizes, int n_in,
                              void* d_out, int out_size, void* d_ws, size_t ws_size,
                              hipStream_t stream) {
    const float* vals   = (const float*)d_in[0];
    const int*   idx    = (const int*)d_in[1];
    const float* gate_w = (const float*)d_in[3];
    const float* gate_b = (const float*)d_in[4];
    const float* attn_w = (const float*)d_in[5];
    const float* attn_b = (const float*)d_in[6];
    float* out = (float*)d_out;

    const int n = in_sizes[1];          // number of nodes
    const int g = out_size / EMB;       // number of graphs (4096)

    // workspace layout (16B-aligned)
    int*   seg_start = (int*)d_ws;                         // g+1 ints
    float* wvec = (float*)((char*)d_ws + (((g + 1) * 4 + 15) & ~15)); // g*EMB floats

    k_bounds<<<(g + 256) / 256, 256, 0, stream>>>(idx, seg_start, n, g);
    k_fused<<<g, 256, 0, stream>>>(vals, gate_w, gate_b, seg_start, wvec);
    k_gemm<<<(g / 64) * 4, 256, 0, stream>>>(wvec, attn_w, attn_b, seg_start, out);
}